// Round 6
// baseline (168.120 us; speedup 1.0000x reference)
//
#include <hip/hip_runtime.h>

namespace {

constexpr int kN = 100;   // subactors
constexpr int kH = 16;    // hidden
constexpr int kS = 6;     // state
constexpr int kB = 128;   // batch
constexpr int kT = 128;   // time
constexpr int kNS = kN * kS;   // 600 floats per (b,t) row
constexpr int kXB = kT * kNS;  // 76800 floats per b
constexpr float kL2E = 1.44269504088896340736f;  // log2(e)

typedef float f32x4 __attribute__((ext_vector_type(4)));
typedef float vf2 __attribute__((ext_vector_type(2)));
typedef short bf16x8 __attribute__((ext_vector_type(8)));

union Frag {
  unsigned u[4];
  bf16x8 v;
};

// Manual RNE pack (proven; r10 showed v_cvt_pk_bf16_f32 breaks numerics).
__device__ __forceinline__ unsigned pkbf(float a, float b) {
  unsigned ua = __builtin_bit_cast(unsigned, a);
  unsigned ub = __builtin_bit_cast(unsigned, b);
  ua += 0x7fffu + ((ua >> 16) & 1u);
  ub += 0x7fffu + ((ub >> 16) & 1u);
  return (ua >> 16) | (ub & 0xffff0000u);
}

__device__ __forceinline__ float rcp_fast(float v) {
  return __builtin_amdgcn_rcpf(v);
}
__device__ __forceinline__ float exp2_fast(float v) {
  return __builtin_amdgcn_exp2f(v);
}
__device__ __forceinline__ vf2 pkfma(vf2 a, vf2 b, vf2 c) {
  return __builtin_elementwise_fma(a, b, c);
}

__device__ __forceinline__ f32x4 mfma16(bf16x8 a, bf16x8 b, f32x4 c) {
  return __builtin_amdgcn_mfma_f32_16x16x32_bf16(a, b, c, 0, 0, 0);
}

// K-slot permutation for lane-local B:
//   quad q supplies k-slots [8q..8q+3] = h rows 4q..4q+3,
//   [8q+4,8q+5] = x comps 2q,2q+1 (q<3), rest 0.
__device__ __forceinline__ void mkA(Frag& F, int qt, const float* hrow,
                                    const float* xrow, float sc) {
  F.u[0] = F.u[1] = F.u[2] = F.u[3] = 0u;
  if (hrow) {
    F.u[0] = pkbf(hrow[4 * qt + 0] * sc, hrow[4 * qt + 1] * sc);
    F.u[1] = pkbf(hrow[4 * qt + 2] * sc, hrow[4 * qt + 3] * sc);
  }
  if (xrow && qt < 3) {
    F.u[2] = pkbf(xrow[2 * qt + 0] * sc, xrow[2 * qt + 1] * sc);
  }
}

}  // namespace

// r23: pure-ILP pairing -- one wave advances TWO independent recurrence
// units (same n, two 16-batch tiles), full epilogue for both, NO LDS, NO
// barrier, NO inter-wave exchange. Rationale: r15 measured 965 cy/step =
// ~540 issue + ~425 single-wave dependence stall; the split/exchange path
// to cut issue is dead (r17: __syncthreads vmcnt drain +440cy/step; r19/
// r21: custom barrier deterministically wrong, identical absmax across two
// fence structures). Pairing attacks the stall instead: two fully
// independent gate chains in one wave fill each other's MFMA/trans
// latency; per-unit-step cost -> issue-bound ~540 cy instead of 965.
// Correct by construction: two r15 instances with disjoint registers,
// shared read-only weight frags. Per-unit FP op order identical to r15 ->
// absmax bit-identical.
__global__ __launch_bounds__(64, 1) void actor_r23(
    const float* __restrict__ x, const float* __restrict__ Wih,
    const float* __restrict__ Whh, const float* __restrict__ bih,
    const float* __restrict__ bhh, const float* __restrict__ W1,
    const float* __restrict__ b1, const float* __restrict__ W2,
    const float* __restrict__ b2, const float* __restrict__ W3,
    const float* __restrict__ b3, float* __restrict__ out) {
  const int tid = (int)threadIdx.x;
  const int j = tid & 15;
  const int qt = tid >> 4;
  const int n = (int)blockIdx.x >> 2;
  const int pr = (int)blockIdx.x & 3;

  // ---- A fragments, K-permuted, log2e-prescaled (shared, same n) ----
  Frag Ar, Az, Anh, Anx, Ay1, Ay2;
  mkA(Ar, qt, Whh + ((size_t)n * 48 + j) * 16, Wih + ((size_t)n * 48 + j) * 6,
      kL2E);
  mkA(Az, qt, Whh + ((size_t)n * 48 + 16 + j) * 16,
      Wih + ((size_t)n * 48 + 16 + j) * 6, kL2E);
  mkA(Anh, qt, Whh + ((size_t)n * 48 + 32 + j) * 16, nullptr, 2.0f * kL2E);
  mkA(Anx, qt, nullptr, Wih + ((size_t)n * 48 + 32 + j) * 6, 2.0f * kL2E);
  mkA(Ay1, qt, W1 + ((size_t)n * 16 + j) * 16, nullptr, 1.0f);
  mkA(Ay2, qt, W2 + ((size_t)n * 16 + j) * 16, nullptr, 1.0f);

  // ---- biases as MFMA C operands (shared, same n) ----
  f32x4 Cbr, Cbz, Cbhn, Cbin, Cb1, Cb2;
  vf2 w301, w323;
#pragma unroll
  for (int r = 0; r < 4; ++r) {
    const int gi = n * 48 + 4 * qt + r;
    Cbr[r] = (bih[gi] + bhh[gi]) * kL2E;
    Cbz[r] = (bih[gi + 16] + bhh[gi + 16]) * kL2E;
    Cbin[r] = bih[gi + 32] * 2.0f * kL2E;
    Cbhn[r] = bhh[gi + 32] * 2.0f * kL2E;
    const int hi = n * 16 + 4 * qt + r;
    Cb1[r] = b1[hi];
    Cb2[r] = b2[hi];
  }
  w301 = (vf2){W3[n * 16 + 4 * qt + 0], W3[n * 16 + 4 * qt + 1]};
  w323 = (vf2){W3[n * 16 + 4 * qt + 2], W3[n * 16 + 4 * qt + 3]};
  const float b3s = b3[n];

  const int bA = (2 * pr + 0) * 16 + j;
  const int bB = (2 * pr + 1) * 16 + j;
  // quad 3 packs x0,x1 too (harmless: its A x-slots are zero, x is finite)
  const int qoff = (qt < 3 ? 2 * qt : 0);
  const float* pxA = x + (size_t)bA * kXB + (size_t)n * kS + qoff;
  const float* pxB = x + (size_t)bB * kXB + (size_t)n * kS + qoff;
  float* outpA = out + ((size_t)n * kB + bA) * kT;
  float* outpB = out + ((size_t)n * kB + bB) * kT;

  // ---- x ping-pong per unit: xa = steps t8..t8+3, xb = t8+4..t8+7 ----
  float2 xaA[4], xbA[4], xaB[4], xbB[4];
#pragma unroll
  for (int i = 0; i < 4; ++i) {
    xaA[i] = *(const float2*)(pxA + (size_t)i * kNS);
    xbA[i] = *(const float2*)(pxA + (size_t)(i + 4) * kNS);
    xaB[i] = *(const float2*)(pxB + (size_t)i * kNS);
    xbB[i] = *(const float2*)(pxB + (size_t)(i + 4) * kNS);
  }

  vf2 hp01A = (vf2){0.f, 0.f}, hp23A = (vf2){0.f, 0.f};
  vf2 hp01B = (vf2){0.f, 0.f}, hp23B = (vf2){0.f, 0.f};
  unsigned P0A = 0u, P1A = 0u, P0B = 0u, P1B = 0u;

  const f32x4 zero4 = {0.f, 0.f, 0.f, 0.f};
  f32x4 Cy1pA = zero4, Cy2pA = zero4;  // y pipeline regs, unit A
  f32x4 Cy1pB = zero4, Cy2pB = zero4;  // unit B
  float s4A[4] = {0.f, 0.f, 0.f, 0.f};
  float s4B[4] = {0.f, 0.f, 0.f, 0.f};

  const vf2 one2 = (vf2){1.f, 1.f};
  const vf2 m2 = (vf2){-2.f, -2.f};
  const vf2 z2 = (vf2){0.f, 0.f};

  // One pipeline step advancing BOTH units one timestep. Stages as r15,
  // duplicated; A/B chunks interleaved at source so the chains mesh.
  auto step = [&](int t, float2 xvA, float2 xvB, bool doRec, bool doA,
                  bool doB_, bool doC) {
    f32x4 CrA, CzA, ChnA, CxnA, Cy1nA = Cy1pA;
    f32x4 CrB, CzB, ChnB, CxnB, Cy1nB = Cy1pB;
    if (t <= kT) {
      Frag BfA, BfB;
      BfA.u[0] = P0A;
      BfA.u[1] = P1A;
      BfA.u[2] = pkbf(xvA.x, xvA.y);
      BfA.u[3] = 0u;
      BfB.u[0] = P0B;
      BfB.u[1] = P1B;
      BfB.u[2] = pkbf(xvB.x, xvB.y);
      BfB.u[3] = 0u;
      if (doRec) {
        CrA = mfma16(Ar.v, BfA.v, Cbr);
        CrB = mfma16(Ar.v, BfB.v, Cbr);
        CzA = mfma16(Az.v, BfA.v, Cbz);
        CzB = mfma16(Az.v, BfB.v, Cbz);
        ChnA = mfma16(Anh.v, BfA.v, Cbhn);
        ChnB = mfma16(Anh.v, BfB.v, Cbhn);
        CxnA = mfma16(Anx.v, BfA.v, Cbin);
        CxnB = mfma16(Anx.v, BfB.v, Cbin);
      }
      Cy1nA = mfma16(Ay1.v, BfA.v, Cb1);  // y1 pre-act for time t-1
      Cy1nB = mfma16(Ay1.v, BfB.v, Cb1);
    }

    // stage B: packed partial s for time t-3 (both units)
    if (doB_) {
      vf2 aA = __builtin_elementwise_max((vf2){Cy2pA[0], Cy2pA[1]}, z2);
      vf2 cA = __builtin_elementwise_max((vf2){Cy2pA[2], Cy2pA[3]}, z2);
      vf2 aB = __builtin_elementwise_max((vf2){Cy2pB[0], Cy2pB[1]}, z2);
      vf2 cB = __builtin_elementwise_max((vf2){Cy2pB[2], Cy2pB[3]}, z2);
      vf2 pA = pkfma(cA, w323, aA * w301);
      vf2 pB = pkfma(cB, w323, aB * w301);
      s4A[(t - 3) & 3] = pA.x + pA.y;
      s4B[(t - 3) & 3] = pB.x + pB.y;
    }

    // stage A: packed relu + RNE pack of y1(time t-2), issue Cy2 (both)
    if (doA) {
      vf2 aA = __builtin_elementwise_max((vf2){Cy1pA[0], Cy1pA[1]}, z2);
      vf2 cA = __builtin_elementwise_max((vf2){Cy1pA[2], Cy1pA[3]}, z2);
      vf2 aB = __builtin_elementwise_max((vf2){Cy1pB[0], Cy1pB[1]}, z2);
      vf2 cB = __builtin_elementwise_max((vf2){Cy1pB[2], Cy1pB[3]}, z2);
      Frag ByA, ByB;
      ByA.u[0] = pkbf(aA.x, aA.y);
      ByA.u[1] = pkbf(cA.x, cA.y);
      ByA.u[2] = 0u;
      ByA.u[3] = 0u;
      ByB.u[0] = pkbf(aB.x, aB.y);
      ByB.u[1] = pkbf(cB.x, cB.y);
      ByB.u[2] = 0u;
      ByB.u[3] = 0u;
      Cy2pA = mfma16(Ay2.v, ByA.v, Cb2);
      Cy2pB = mfma16(Ay2.v, ByB.v, Cb2);
    }

    // stage C: batched 16-lane reduce + float4 store, times t-6..t-3 (both)
    if (doC) {
      float a0 = s4A[0], a1 = s4A[1], a2 = s4A[2], a3 = s4A[3];
      float b0 = s4B[0], b1v = s4B[1], b2v = s4B[2], b3v = s4B[3];
      a0 += __shfl_xor(a0, 16);
      a1 += __shfl_xor(a1, 16);
      a2 += __shfl_xor(a2, 16);
      a3 += __shfl_xor(a3, 16);
      b0 += __shfl_xor(b0, 16);
      b1v += __shfl_xor(b1v, 16);
      b2v += __shfl_xor(b2v, 16);
      b3v += __shfl_xor(b3v, 16);
      a0 += __shfl_xor(a0, 32);
      a1 += __shfl_xor(a1, 32);
      a2 += __shfl_xor(a2, 32);
      a3 += __shfl_xor(a3, 32);
      b0 += __shfl_xor(b0, 32);
      b1v += __shfl_xor(b1v, 32);
      b2v += __shfl_xor(b2v, 32);
      b3v += __shfl_xor(b3v, 32);
      if (qt == 0) {
        float4 oA = {fmaxf(a0 + b3s, 0.f), fmaxf(a1 + b3s, 0.f),
                     fmaxf(a2 + b3s, 0.f), fmaxf(a3 + b3s, 0.f)};
        float4 oB = {fmaxf(b0 + b3s, 0.f), fmaxf(b1v + b3s, 0.f),
                     fmaxf(b2v + b3s, 0.f), fmaxf(b3v + b3s, 0.f)};
        *(float4*)(outpA + (t - 6)) = oA;
        *(float4*)(outpB + (t - 6)) = oB;
      }
    }

    // packed gate epilogue -> h_t, both units, chunks interleaved. FP op
    // order within each unit identical to r15.
    if (doRec) {
      vf2 cr01A = {CrA[0], CrA[1]}, cr23A = {CrA[2], CrA[3]};
      vf2 cz01A = {CzA[0], CzA[1]}, cz23A = {CzA[2], CzA[3]};
      vf2 cr01B = {CrB[0], CrB[1]}, cr23B = {CrB[2], CrB[3]};
      vf2 cz01B = {CzB[0], CzB[1]}, cz23B = {CzB[2], CzB[3]};
      vf2 chn01A = {ChnA[0], ChnA[1]}, chn23A = {ChnA[2], ChnA[3]};
      vf2 cxn01A = {CxnA[0], CxnA[1]}, cxn23A = {CxnA[2], CxnA[3]};
      vf2 chn01B = {ChnB[0], ChnB[1]}, chn23B = {ChnB[2], ChnB[3]};
      vf2 cxn01B = {CxnB[0], CxnB[1]}, cxn23B = {CxnB[2], CxnB[3]};

      vf2 er01A = {exp2_fast(-cr01A.x), exp2_fast(-cr01A.y)};
      vf2 er23A = {exp2_fast(-cr23A.x), exp2_fast(-cr23A.y)};
      vf2 er01B = {exp2_fast(-cr01B.x), exp2_fast(-cr01B.y)};
      vf2 er23B = {exp2_fast(-cr23B.x), exp2_fast(-cr23B.y)};
      vf2 ez01A = {exp2_fast(-cz01A.x), exp2_fast(-cz01A.y)};
      vf2 ez23A = {exp2_fast(-cz23A.x), exp2_fast(-cz23A.y)};
      vf2 ez01B = {exp2_fast(-cz01B.x), exp2_fast(-cz01B.y)};
      vf2 ez23B = {exp2_fast(-cz23B.x), exp2_fast(-cz23B.y)};

      vf2 dr01A = er01A + one2, dr23A = er23A + one2;
      vf2 dr01B = er01B + one2, dr23B = er23B + one2;
      vf2 rr01A = {rcp_fast(dr01A.x), rcp_fast(dr01A.y)};
      vf2 rr23A = {rcp_fast(dr23A.x), rcp_fast(dr23A.y)};
      vf2 rr01B = {rcp_fast(dr01B.x), rcp_fast(dr01B.y)};
      vf2 rr23B = {rcp_fast(dr23B.x), rcp_fast(dr23B.y)};

      vf2 dz01A = ez01A + one2, dz23A = ez23A + one2;
      vf2 dz01B = ez01B + one2, dz23B = ez23B + one2;
      vf2 zz01A = {rcp_fast(dz01A.x), rcp_fast(dz01A.y)};
      vf2 zz23A = {rcp_fast(dz23A.x), rcp_fast(dz23A.y)};
      vf2 zz01B = {rcp_fast(dz01B.x), rcp_fast(dz01B.y)};
      vf2 zz23B = {rcp_fast(dz23B.x), rcp_fast(dz23B.y)};

      vf2 np01A = pkfma(rr01A, chn01A, cxn01A);
      vf2 np23A = pkfma(rr23A, chn23A, cxn23A);
      vf2 np01B = pkfma(rr01B, chn01B, cxn01B);
      vf2 np23B = pkfma(rr23B, chn23B, cxn23B);
      vf2 en01A = {exp2_fast(np01A.x), exp2_fast(np01A.y)};
      vf2 en23A = {exp2_fast(np23A.x), exp2_fast(np23A.y)};
      vf2 en01B = {exp2_fast(np01B.x), exp2_fast(np01B.y)};
      vf2 en23B = {exp2_fast(np23B.x), exp2_fast(np23B.y)};
      vf2 dn01A = en01A + one2, dn23A = en23A + one2;
      vf2 dn01B = en01B + one2, dn23B = en23B + one2;
      vf2 rn01A = {rcp_fast(dn01A.x), rcp_fast(dn01A.y)};
      vf2 rn23A = {rcp_fast(dn23A.x), rcp_fast(dn23A.y)};
      vf2 rn01B = {rcp_fast(dn01B.x), rcp_fast(dn01B.y)};
      vf2 rn23B = {rcp_fast(dn23B.x), rcp_fast(dn23B.y)};
      vf2 nn01A = pkfma(m2, rn01A, one2);
      vf2 nn23A = pkfma(m2, rn23A, one2);
      vf2 nn01B = pkfma(m2, rn01B, one2);
      vf2 nn23B = pkfma(m2, rn23B, one2);

      hp01A = pkfma(zz01A, hp01A - nn01A, nn01A);
      hp23A = pkfma(zz23A, hp23A - nn23A, nn23A);
      hp01B = pkfma(zz01B, hp01B - nn01B, nn01B);
      hp23B = pkfma(zz23B, hp23B - nn23B, nn23B);
      P0A = pkbf(hp01A.x, hp01A.y);
      P1A = pkbf(hp23A.x, hp23A.y);
      P0B = pkbf(hp01B.x, hp01B.y);
      P1B = pkbf(hp23B.x, hp23B.y);
    }

    Cy1pA = Cy1nA;
    Cy1pB = Cy1nB;
  };

  // main loop: 8-step windows, x ping-pong refilled with >=4 steps slack.
  for (int t8 = 0; t8 < kT; t8 += 8) {
    const bool p0 = (t8 > 0);  // stages active after pipeline fill
    step(t8 + 0, xaA[0], xaB[0], true, p0, p0, false);
    step(t8 + 1, xaA[1], xaB[1], true, true, p0, false);
    step(t8 + 2, xaA[2], xaB[2], true, true, true, p0);
    step(t8 + 3, xaA[3], xaB[3], true, true, true, false);
#pragma unroll
    for (int i = 0; i < 4; ++i) {
      int tc = t8 + 8 + i;
      if (tc > kT - 1) tc = kT - 1;
      xaA[i] = *(const float2*)(pxA + (size_t)tc * kNS);
      xaB[i] = *(const float2*)(pxB + (size_t)tc * kNS);
    }
    step(t8 + 4, xbA[0], xbB[0], true, true, true, false);
    step(t8 + 5, xbA[1], xbB[1], true, true, true, false);
    step(t8 + 6, xbA[2], xbB[2], true, true, true, true);
    step(t8 + 7, xbA[3], xbB[3], true, true, true, false);
#pragma unroll
    for (int i = 0; i < 4; ++i) {
      int tc = t8 + 12 + i;
      if (tc > kT - 1) tc = kT - 1;
      xbA[i] = *(const float2*)(pxA + (size_t)tc * kNS);
      xbB[i] = *(const float2*)(pxB + (size_t)tc * kNS);
    }
  }

  // drain (x no longer consumed), both units
  const float2 xz = {0.f, 0.f};
  step(kT, xz, xz, false, true, true, false);
  step(kT + 1, xz, xz, false, true, true, false);
  step(kT + 2, xz, xz, false, false, true, true);  // stores times 124..127
}

extern "C" void kernel_launch(void* const* d_in, const int* in_sizes, int n_in,
                              void* d_out, int out_size, void* d_ws,
                              size_t ws_size, hipStream_t stream) {
  const float* x = (const float*)d_in[0];
  const float* Wih = (const float*)d_in[1];
  const float* Whh = (const float*)d_in[2];
  const float* bih = (const float*)d_in[3];
  const float* bhh = (const float*)d_in[4];
  const float* W1 = (const float*)d_in[5];
  const float* b1 = (const float*)d_in[6];
  const float* W2 = (const float*)d_in[7];
  const float* b2 = (const float*)d_in[8];
  const float* W3 = (const float*)d_in[9];
  const float* b3 = (const float*)d_in[10];
  float* out = (float*)d_out;

  actor_r23<<<dim3(kN * 4), dim3(64), 0, stream>>>(x, Wih, Whh, bih, bhh, W1,
                                                   b1, W2, b2, W3, b3, out);
}

// Round 7
// 134.106 us; speedup vs baseline: 1.2536x; 1.2536x over previous
//
#include <hip/hip_runtime.h>

namespace {

constexpr int kN = 100;   // subactors
constexpr int kH = 16;    // hidden
constexpr int kS = 6;     // state
constexpr int kB = 128;   // batch
constexpr int kT = 128;   // time
constexpr int kNS = kN * kS;   // 600 floats per (b,t) row
constexpr int kXB = kT * kNS;  // 76800 floats per b
constexpr float kL2E = 1.44269504088896340736f;  // log2(e)

typedef float f32x4 __attribute__((ext_vector_type(4)));
typedef float vf2 __attribute__((ext_vector_type(2)));
typedef short bf16x8 __attribute__((ext_vector_type(8)));

union Frag {
  unsigned u[4];
  bf16x8 v;
};

// Manual RNE pack (proven; r10 showed v_cvt_pk_bf16_f32 breaks numerics).
// r25: final combine via v_perm_b32 (bitwise-identical to
// (ua>>16)|(ub&0xffff0000): low16 = a's bf16, high16 = b's bf16).
__device__ __forceinline__ unsigned pkbf(float a, float b) {
  unsigned ua = __builtin_bit_cast(unsigned, a);
  unsigned ub = __builtin_bit_cast(unsigned, b);
  ua += 0x7fffu + ((ua >> 16) & 1u);
  ub += 0x7fffu + ((ub >> 16) & 1u);
  return __builtin_amdgcn_perm(ua, ub, 0x03020706u);
}

__device__ __forceinline__ float rcp_fast(float v) {
  return __builtin_amdgcn_rcpf(v);
}
__device__ __forceinline__ float exp2_fast(float v) {
  return __builtin_amdgcn_exp2f(v);
}
__device__ __forceinline__ vf2 pkfma(vf2 a, vf2 b, vf2 c) {
  return __builtin_elementwise_fma(a, b, c);
}

__device__ __forceinline__ f32x4 mfma16(bf16x8 a, bf16x8 b, f32x4 c) {
  return __builtin_amdgcn_mfma_f32_16x16x32_bf16(a, b, c, 0, 0, 0);
}

// K-slot permutation for lane-local B:
//   quad q supplies k-slots [8q..8q+3] = h rows 4q..4q+3,
//   [8q+4,8q+5] = x comps 2q,2q+1 (q<3), rest 0.
__device__ __forceinline__ void mkA(Frag& F, int qt, const float* hrow,
                                    const float* xrow, float sc) {
  F.u[0] = F.u[1] = F.u[2] = F.u[3] = 0u;
  if (hrow) {
    F.u[0] = pkbf(hrow[4 * qt + 0] * sc, hrow[4 * qt + 1] * sc);
    F.u[1] = pkbf(hrow[4 * qt + 2] * sc, hrow[4 * qt + 3] * sc);
  }
  if (xrow && qt < 3) {
    F.u[2] = pkbf(xrow[2 * qt + 0] * sc, xrow[2 * qt + 1] * sc);
  }
}

}  // namespace

// r25: r15 structure (wave = (n, 16-batch tile), 800 waves, lane-local B,
// y-path pipelined 2 deep, packed epilogue, bias-in-C, exp2-native, x
// ping-pong) -- the session's measured best (52.3us dispatch) -- with two
// bit-exact micro-opts:
//   1. pkbf's final combine as v_perm_b32 (saves ~1 instr x ~11 packs/step).
//   2. amdgpu_waves_per_eu(1,1): 800 waves on 1024 SIMDs can never exceed
//      1 wave/EU, so cap the scheduler's occupancy target at exactly 1,
//      removing any register-pressure-driven serialization.
// Structural alternatives are measured-dead: 2-wave h-split (r17 +440cy/
// step __syncthreads vmcnt drain; r19/r21 custom barrier deterministically
// wrong), pure-ILP pairing (r23: per-unit 965->805 cy but halved occupancy
// -> wall 88us). The kernel is latency-bound with units(800) < SIMDs(1024);
// only issue-floor shaving remains.
__global__ __launch_bounds__(64)
__attribute__((amdgpu_waves_per_eu(1, 1))) void actor_r25(
    const float* __restrict__ x, const float* __restrict__ Wih,
    const float* __restrict__ Whh, const float* __restrict__ bih,
    const float* __restrict__ bhh, const float* __restrict__ W1,
    const float* __restrict__ b1, const float* __restrict__ W2,
    const float* __restrict__ b2, const float* __restrict__ W3,
    const float* __restrict__ b3, float* __restrict__ out) {
  const int tid = (int)threadIdx.x;
  const int j = tid & 15;
  const int qt = tid >> 4;
  const int n = (int)blockIdx.x >> 3;
  const int bt = (int)blockIdx.x & 7;

  // ---- A fragments, K-permuted, log2e-prescaled ----
  Frag Ar, Az, Anh, Anx, Ay1, Ay2;
  mkA(Ar, qt, Whh + ((size_t)n * 48 + j) * 16, Wih + ((size_t)n * 48 + j) * 6,
      kL2E);
  mkA(Az, qt, Whh + ((size_t)n * 48 + 16 + j) * 16,
      Wih + ((size_t)n * 48 + 16 + j) * 6, kL2E);
  mkA(Anh, qt, Whh + ((size_t)n * 48 + 32 + j) * 16, nullptr, 2.0f * kL2E);
  mkA(Anx, qt, nullptr, Wih + ((size_t)n * 48 + 32 + j) * 6, 2.0f * kL2E);
  mkA(Ay1, qt, W1 + ((size_t)n * 16 + j) * 16, nullptr, 1.0f);
  mkA(Ay2, qt, W2 + ((size_t)n * 16 + j) * 16, nullptr, 1.0f);

  // ---- biases as MFMA C operands ----
  f32x4 Cbr, Cbz, Cbhn, Cbin, Cb1, Cb2;
  vf2 w301, w323;
#pragma unroll
  for (int r = 0; r < 4; ++r) {
    const int gi = n * 48 + 4 * qt + r;
    Cbr[r] = (bih[gi] + bhh[gi]) * kL2E;
    Cbz[r] = (bih[gi + 16] + bhh[gi + 16]) * kL2E;
    Cbin[r] = bih[gi + 32] * 2.0f * kL2E;
    Cbhn[r] = bhh[gi + 32] * 2.0f * kL2E;
    const int hi = n * 16 + 4 * qt + r;
    Cb1[r] = b1[hi];
    Cb2[r] = b2[hi];
  }
  w301 = (vf2){W3[n * 16 + 4 * qt + 0], W3[n * 16 + 4 * qt + 1]};
  w323 = (vf2){W3[n * 16 + 4 * qt + 2], W3[n * 16 + 4 * qt + 3]};
  const float b3s = b3[n];

  const int b = bt * 16 + j;
  // quad 3 packs x0,x1 too (harmless: its A x-slots are zero, x is finite)
  const float* px =
      x + (size_t)b * kXB + (size_t)n * kS + (qt < 3 ? 2 * qt : 0);
  float* outp = out + ((size_t)n * kB + b) * kT;

  // ---- x ping-pong: xa = steps t8..t8+3, xb = t8+4..t8+7 ----
  float2 xa[4], xb[4];
#pragma unroll
  for (int i = 0; i < 4; ++i) {
    xa[i] = *(const float2*)(px + (size_t)i * kNS);
    xb[i] = *(const float2*)(px + (size_t)(i + 4) * kNS);
  }

  vf2 hp01 = (vf2){0.f, 0.f}, hp23 = (vf2){0.f, 0.f};
  unsigned P0 = 0u, P1 = 0u;

  const f32x4 zero4 = {0.f, 0.f, 0.f, 0.f};
  f32x4 Cy1p = zero4;  // Cy1 issued previous step (time t-2 at step t)
  f32x4 Cy2p = zero4;  // Cy2 issued previous step (time t-3 at step t)
  float s4[4] = {0.f, 0.f, 0.f, 0.f};

  const vf2 one2 = (vf2){1.f, 1.f};
  const vf2 m2 = (vf2){-2.f, -2.f};
  const vf2 z2 = (vf2){0.f, 0.f};

  // One pipeline step consuming pre-loaded x (xv). Stages as in r15.
  auto step = [&](int t, float2 xv, bool doRec, bool doA, bool doB,
                  bool doC) {
    f32x4 Cr, Cz, Chn, Cxn, Cy1n = Cy1p;
    if (t <= kT) {
      Frag Bf;
      Bf.u[0] = P0;
      Bf.u[1] = P1;
      Bf.u[2] = pkbf(xv.x, xv.y);
      Bf.u[3] = 0u;
      if (doRec) {
        Cr = mfma16(Ar.v, Bf.v, Cbr);
        Cz = mfma16(Az.v, Bf.v, Cbz);
        Chn = mfma16(Anh.v, Bf.v, Cbhn);
        Cxn = mfma16(Anx.v, Bf.v, Cbin);
      }
      Cy1n = mfma16(Ay1.v, Bf.v, Cb1);  // y1 pre-act for time t-1
    }

    // stage B: packed partial s for time t-3 from Cy2p (fills MFMA latency)
    if (doB) {
      vf2 a = __builtin_elementwise_max((vf2){Cy2p[0], Cy2p[1]}, z2);
      vf2 c = __builtin_elementwise_max((vf2){Cy2p[2], Cy2p[3]}, z2);
      vf2 p = pkfma(c, w323, a * w301);
      s4[(t - 3) & 3] = p.x + p.y;
    }

    // stage A: packed relu + RNE pack of y1(time t-2), issue Cy2
    if (doA) {
      vf2 a = __builtin_elementwise_max((vf2){Cy1p[0], Cy1p[1]}, z2);
      vf2 c = __builtin_elementwise_max((vf2){Cy1p[2], Cy1p[3]}, z2);
      Frag By;
      By.u[0] = pkbf(a.x, a.y);
      By.u[1] = pkbf(c.x, c.y);
      By.u[2] = 0u;
      By.u[3] = 0u;
      Cy2p = mfma16(Ay2.v, By.v, Cb2);
    }

    // epilogue phase 1: r/z exp2 block as soon as Cr/Cz land
    vf2 cr01, cr23, cz01, cz23;
    vf2 er01, er23, ez01, ez23;
    if (doRec) {
      cr01 = (vf2){Cr[0], Cr[1]};
      cr23 = (vf2){Cr[2], Cr[3]};
      cz01 = (vf2){Cz[0], Cz[1]};
      cz23 = (vf2){Cz[2], Cz[3]};
      er01 = (vf2){exp2_fast(-cr01.x), exp2_fast(-cr01.y)};
      er23 = (vf2){exp2_fast(-cr23.x), exp2_fast(-cr23.y)};
      ez01 = (vf2){exp2_fast(-cz01.x), exp2_fast(-cz01.y)};
      ez23 = (vf2){exp2_fast(-cz23.x), exp2_fast(-cz23.y)};
    }

    // stage C: batched 16-lane reduce + float4 store of times t-6..t-3.
    if (doC) {
      float v0 = s4[0], v1 = s4[1], v2 = s4[2], v3 = s4[3];
      v0 += __shfl_xor(v0, 16);
      v1 += __shfl_xor(v1, 16);
      v2 += __shfl_xor(v2, 16);
      v3 += __shfl_xor(v3, 16);
      v0 += __shfl_xor(v0, 32);
      v1 += __shfl_xor(v1, 32);
      v2 += __shfl_xor(v2, 32);
      v3 += __shfl_xor(v3, 32);
      if (qt == 0) {
        float4 o = {fmaxf(v0 + b3s, 0.f), fmaxf(v1 + b3s, 0.f),
                    fmaxf(v2 + b3s, 0.f), fmaxf(v3 + b3s, 0.f)};
        *(float4*)(outp + (t - 6)) = o;
      }
    }

    // epilogue phase 2: sigmoids, n-gate chain, h update (FP op order
    // identical to r15)
    if (doRec) {
      vf2 chn01 = {Chn[0], Chn[1]}, chn23 = {Chn[2], Chn[3]};
      vf2 cxn01 = {Cxn[0], Cxn[1]}, cxn23 = {Cxn[2], Cxn[3]};

      vf2 dr01 = er01 + one2, dr23 = er23 + one2;
      vf2 rr01 = {rcp_fast(dr01.x), rcp_fast(dr01.y)};
      vf2 rr23 = {rcp_fast(dr23.x), rcp_fast(dr23.y)};

      vf2 dz01 = ez01 + one2, dz23 = ez23 + one2;
      vf2 zz01 = {rcp_fast(dz01.x), rcp_fast(dz01.y)};
      vf2 zz23 = {rcp_fast(dz23.x), rcp_fast(dz23.y)};

      vf2 np01 = pkfma(rr01, chn01, cxn01);
      vf2 np23 = pkfma(rr23, chn23, cxn23);
      vf2 en01 = {exp2_fast(np01.x), exp2_fast(np01.y)};
      vf2 en23 = {exp2_fast(np23.x), exp2_fast(np23.y)};
      vf2 dn01 = en01 + one2, dn23 = en23 + one2;
      vf2 rn01 = {rcp_fast(dn01.x), rcp_fast(dn01.y)};
      vf2 rn23 = {rcp_fast(dn23.x), rcp_fast(dn23.y)};
      vf2 nn01 = pkfma(m2, rn01, one2);
      vf2 nn23 = pkfma(m2, rn23, one2);

      hp01 = pkfma(zz01, hp01 - nn01, nn01);
      hp23 = pkfma(zz23, hp23 - nn23, nn23);
      P0 = pkbf(hp01.x, hp01.y);
      P1 = pkbf(hp23.x, hp23.y);
    }

    Cy1p = Cy1n;
  };

  // main loop: 8-step windows. First half consumes xa then refills xa with
  // t8+8..t8+11 (consumed next window, >=4 steps of slack); second half
  // likewise for xb.
  for (int t8 = 0; t8 < kT; t8 += 8) {
    const bool p0 = (t8 > 0);          // stages active after pipeline fill
    step(t8 + 0, xa[0], true, p0 || false, p0, false);
    step(t8 + 1, xa[1], true, true, p0, false);
    step(t8 + 2, xa[2], true, true, true, p0);
    step(t8 + 3, xa[3], true, true, true, false);
#pragma unroll
    for (int i = 0; i < 4; ++i) {
      int tc = t8 + 8 + i;
      if (tc > kT - 1) tc = kT - 1;
      xa[i] = *(const float2*)(px + (size_t)tc * kNS);
    }
    step(t8 + 4, xb[0], true, true, true, false);
    step(t8 + 5, xb[1], true, true, true, false);
    step(t8 + 6, xb[2], true, true, true, true);
    step(t8 + 7, xb[3], true, true, true, false);
#pragma unroll
    for (int i = 0; i < 4; ++i) {
      int tc = t8 + 12 + i;
      if (tc > kT - 1) tc = kT - 1;
      xb[i] = *(const float2*)(px + (size_t)tc * kNS);
    }
  }

  // drain (x no longer consumed)
  const float2 xz = {0.f, 0.f};
  step(kT, xz, false, true, true, false);
  step(kT + 1, xz, false, true, true, false);
  step(kT + 2, xz, false, false, true, true);  // stores times 124..127
}

extern "C" void kernel_launch(void* const* d_in, const int* in_sizes, int n_in,
                              void* d_out, int out_size, void* d_ws,
                              size_t ws_size, hipStream_t stream) {
  const float* x = (const float*)d_in[0];
  const float* Wih = (const float*)d_in[1];
  const float* Whh = (const float*)d_in[2];
  const float* bih = (const float*)d_in[3];
  const float* bhh = (const float*)d_in[4];
  const float* W1 = (const float*)d_in[5];
  const float* b1 = (const float*)d_in[6];
  const float* W2 = (const float*)d_in[7];
  const float* b2 = (const float*)d_in[8];
  const float* W3 = (const float*)d_in[9];
  const float* b3 = (const float*)d_in[10];
  float* out = (float*)d_out;

  actor_r25<<<dim3(kN * 8), dim3(64), 0, stream>>>(x, Wih, Whh, bih, bhh, W1,
                                                   b1, W2, b2, W3, b3, out);
}